// Round 1
// 777.765 us; speedup vs baseline: 1.0556x; 1.0556x over previous
//
#include <hip/hip_runtime.h>
#include <stdint.h>

// Problem constants (match reference)
#define USER_N 100000
#define ITEM_N 50000
#define TAG_N  20000
#define NN (USER_N + ITEM_N)   // 150000 interaction-graph nodes
#define MM (ITEM_N + TAG_N)    // 70000 tag-graph nodes
#define DD 64
#define NPART 8                // one row-partition per XCD (MI355X has 8 XCDs)

// ---------------------------------------------------------------------------
// JAX threefry2x32 (20 rounds), bit-exact (verified: R1 absmax 0.0).
// ---------------------------------------------------------------------------
__host__ __device__ __forceinline__ void tf2x32(uint32_t k0, uint32_t k1,
                                                uint32_t x0, uint32_t x1,
                                                uint32_t* o0, uint32_t* o1) {
  uint32_t ks2 = k0 ^ k1 ^ 0x1BD11BDAu;
#define ROTL32(v, d) (((v) << (d)) | ((v) >> (32 - (d))))
#define TF_RND(d) { x0 += x1; x1 = ROTL32(x1, d); x1 ^= x0; }
  x0 += k0; x1 += k1;
  TF_RND(13) TF_RND(15) TF_RND(26) TF_RND(6)
  x0 += k1;  x1 += ks2 + 1u;
  TF_RND(17) TF_RND(29) TF_RND(16) TF_RND(24)
  x0 += ks2; x1 += k0 + 2u;
  TF_RND(13) TF_RND(15) TF_RND(26) TF_RND(6)
  x0 += k0;  x1 += k1 + 3u;
  TF_RND(17) TF_RND(29) TF_RND(16) TF_RND(24)
  x0 += k1;  x1 += ks2 + 4u;
  TF_RND(13) TF_RND(15) TF_RND(26) TF_RND(6)
  x0 += ks2; x1 += k0 + 5u;
  *o0 = x0; *o1 = x1;
#undef TF_RND
#undef ROTL32
}

// keep-mask(e; key), bit-exact vs jax uniform+floor
__device__ __forceinline__ float drop_mask(uint32_t e, uint32_t k0, uint32_t k1) {
  uint32_t o0, o1;
  tf2x32(k0, k1, 0u, e, &o0, &o1);
  uint32_t bits = o0 ^ o1;
  float u = __uint_as_float((bits >> 9) | 0x3F800000u) - 1.0f;
  return floorf(u + 0.9f);
}

// bf16 helpers: RNE pack, exact shl unpack
__device__ __forceinline__ uint32_t f2bf(float f) {
  uint32_t u = __float_as_uint(f);
  return (u + 0x7fffu + ((u >> 16) & 1u)) >> 16;
}
__device__ __forceinline__ float bflo(uint32_t u) { return __uint_as_float(u << 16); }
__device__ __forceinline__ float bfhi(uint32_t u) { return __uint_as_float(u & 0xffff0000u); }

// ---------------------------------------------------------------------------
// CSR build (R9 structure): histpack -> hierarchical scan -> PARTITIONED
// scatter. R8's fused scatter showed WRITE_SIZE = 125 MB for a 16 MB rec
// region (8x amplification: every 8 B record = one 64 B partial-line HBM
// transaction, because a line's 8 records arrive from arbitrary XCDs whose
// L2s are not coherent). Fix: partition rows into 8 contiguous ranges;
// partition p is scattered only by blocks with blockIdx%8==p, which the
// round-robin dispatcher places on XCD p. Each partition's ~2 MB rec region
// then stays in ONE XCD's 4 MB L2 and lines coalesce before writeback.
// Correctness is independent of the blockIdx->XCD mapping (each edge owned
// by exactly one partition; atomics are device-scope); only locality rides
// on round-robin. Streaming reads use nontemporal loads so they don't evict
// rec lines between a line's temporally-spread writes.
// ---------------------------------------------------------------------------

// Coalesced pass: histogram atomic + threefry drop masks for BOTH layers,
// packed 2x bf16 into pk[e] (full lane utilization; pk write is coalesced).
__global__ void histpack_kernel(const int* __restrict__ rows, const float* __restrict__ vals,
                                int* __restrict__ cnt, uint32_t* __restrict__ pk, int nE,
                                uint32_t ka0, uint32_t ka1, uint32_t kb0, uint32_t kb1) {
  int e = blockIdx.x * blockDim.x + threadIdx.x;
  if (e >= nE) return;
  atomicAdd(&cnt[rows[e]], 1);
  const float SC = (float)(1.0 / 0.9);
  float v  = vals[e];
  float v0 = v * drop_mask((uint32_t)e, ka0, ka1) * SC;
  float v1 = v * drop_mask((uint32_t)e, kb0, kb1) * SC;
  pk[e] = f2bf(v0) | (f2bf(v1) << 16);   // dropped -> exact 0 bits
}

__global__ void scan1_kernel(const int* __restrict__ cnt, int* __restrict__ rp,
                             int* __restrict__ bsum, int n) {
  __shared__ int s[256];
  int t = threadIdx.x;
  int base = blockIdx.x * 1024 + t * 4;
  int c0 = (base + 0 < n) ? cnt[base + 0] : 0;
  int c1 = (base + 1 < n) ? cnt[base + 1] : 0;
  int c2 = (base + 2 < n) ? cnt[base + 2] : 0;
  int c3 = (base + 3 < n) ? cnt[base + 3] : 0;
  int tsum = c0 + c1 + c2 + c3;
  s[t] = tsum;
  __syncthreads();
  for (int off = 1; off < 256; off <<= 1) {
    int v = (t >= off) ? s[t - off] : 0;
    __syncthreads();
    s[t] += v;
    __syncthreads();
  }
  int excl = s[t] - tsum;
  if (base + 0 < n) rp[base + 0] = excl;
  if (base + 1 < n) rp[base + 1] = excl + c0;
  if (base + 2 < n) rp[base + 2] = excl + c0 + c1;
  if (base + 3 < n) rp[base + 3] = excl + c0 + c1 + c2;
  if (t == 255) bsum[blockIdx.x] = s[255];
}

__global__ void scan2_kernel(int* __restrict__ bsum, int B) {
  __shared__ int s[256];
  int t = threadIdx.x;
  int v = (t < B) ? bsum[t] : 0;
  s[t] = v;
  __syncthreads();
  for (int off = 1; off < 256; off <<= 1) {
    int x = (t >= off) ? s[t - off] : 0;
    __syncthreads();
    s[t] += x;
    __syncthreads();
  }
  if (t < B) bsum[t] = s[t] - v;
}

__global__ void scan3_kernel(int* __restrict__ rp, const int* __restrict__ bsum,
                             int* __restrict__ cursor, int n, int nE) {
  int i = blockIdx.x * blockDim.x + threadIdx.x;
  if (i < n) {
    int v = rp[i] + bsum[i >> 10];
    rp[i] = v;
    cursor[i] = v;
  }
  if (i == 0) rp[n] = nE;
}

// XCD-partitioned scatter: block (p, slice) scans edge slice, scatters only
// edges whose row falls in partition p's contiguous row range. Light body:
// no threefry here (pk precomputed). Masked lanes idle during the owned-edge
// loads, but total instruction issue is small; the lever is L2-local writes.
__global__ void scatter_part_kernel(const int* __restrict__ rows, const int* __restrict__ cols,
                                    const uint32_t* __restrict__ pk,
                                    int* __restrict__ cursor, int2* __restrict__ rec,
                                    int nE, int nRows, int nSlices) {
  int p     = blockIdx.x & (NPART - 1);
  int slice = blockIdx.x >> 3;
  int lo = (int)((long long)p * nRows / NPART);
  int hi = (int)((long long)(p + 1) * nRows / NPART);
  int per = (nE + nSlices - 1) / nSlices;
  int e0 = slice * per;
  int e1 = e0 + per; if (e1 > nE) e1 = nE;
  for (int e = e0 + (int)threadIdx.x; e < e1; e += (int)blockDim.x) {
    int r = __builtin_nontemporal_load(&rows[e]);
    if (r >= lo && r < hi) {
      int      c = __builtin_nontemporal_load(&cols[e]);
      uint32_t w = __builtin_nontemporal_load(&pk[e]);
      int pos = atomicAdd(&cursor[r], 1);
      rec[pos] = make_int2(c, (int)w);
    }
  }
}

// ---------------------------------------------------------------------------
// Gather SpMM core, eighth-wave bf16 (R8): row = 64 bf16 = 8 lanes x uint4.
// Wave = 8 sub-groups of 8 lanes; group `sub` handles edge j+sub -> 8 edges
// per load instruction. WAVE-UNIFORM trip counts (R3 lesson): loop bounds
// depend only on uniform cnt; shfl idx j+sub <= 63 always; OOB/dropped edges
// have v = exact 0 (guard skips their load; guard is sub-group-uniform).
// Cross-subgroup reduce via shfl_xor(8/16/32). VS picks the layer value.
// ---------------------------------------------------------------------------
template <int VS>
__device__ __forceinline__ void gather_row8(int s0, int s1, const int2* __restrict__ rec,
                                            const ushort* __restrict__ srcA,
                                            const ushort* __restrict__ srcB,
                                            int split, int lane, int sub, int fl,
                                            float4& A0, float4& A1) {
  float4 a0 = make_float4(0.f, 0.f, 0.f, 0.f);
  float4 a1 = make_float4(0.f, 0.f, 0.f, 0.f);
  for (int base = s0; base < s1; base += 64) {
    int i = base + lane;
    int2 m = make_int2(0, 0);            // pad: col 0, v 0 (exact +0)
    if (i < s1) m = rec[i];
    int cnt = s1 - base;
    if (cnt > 64) cnt = 64;
    int j = 0;
    for (; j + 16 <= cnt; j += 16) {     // 2 independent edges per sub-group
      int      cA = __shfl(m.x, j + sub);
      uint32_t wA = (uint32_t)__shfl(m.y, j + sub);
      int      cB = __shfl(m.x, j + 8 + sub);
      uint32_t wB = (uint32_t)__shfl(m.y, j + 8 + sub);
      float vA = VS ? bfhi(wA) : bflo(wA);
      float vB = VS ? bfhi(wB) : bflo(wB);
      if (vA != 0.0f) {
        const ushort* p = (cA < split) ? srcA + (size_t)cA * DD : srcB + (size_t)(cA - split) * DD;
        uint4 q = ((const uint4*)p)[fl];
        a0.x += vA * bflo(q.x); a0.y += vA * bfhi(q.x);
        a0.z += vA * bflo(q.y); a0.w += vA * bfhi(q.y);
        a1.x += vA * bflo(q.z); a1.y += vA * bfhi(q.z);
        a1.z += vA * bflo(q.w); a1.w += vA * bfhi(q.w);
      }
      if (vB != 0.0f) {
        const ushort* p = (cB < split) ? srcA + (size_t)cB * DD : srcB + (size_t)(cB - split) * DD;
        uint4 q = ((const uint4*)p)[fl];
        a0.x += vB * bflo(q.x); a0.y += vB * bfhi(q.x);
        a0.z += vB * bflo(q.y); a0.w += vB * bfhi(q.y);
        a1.x += vB * bflo(q.z); a1.y += vB * bfhi(q.z);
        a1.z += vB * bflo(q.w); a1.w += vB * bfhi(q.w);
      }
    }
    for (; j < cnt; j += 8) {
      int      c = __shfl(m.x, j + sub);
      uint32_t w = (uint32_t)__shfl(m.y, j + sub);
      float v = VS ? bfhi(w) : bflo(w);
      if (v != 0.0f) {
        const ushort* p = (c < split) ? srcA + (size_t)c * DD : srcB + (size_t)(c - split) * DD;
        uint4 q = ((const uint4*)p)[fl];
        a0.x += v * bflo(q.x); a0.y += v * bfhi(q.x);
        a0.z += v * bflo(q.y); a0.w += v * bfhi(q.y);
        a1.x += v * bflo(q.z); a1.y += v * bfhi(q.z);
        a1.z += v * bflo(q.w); a1.w += v * bfhi(q.w);
      }
    }
  }
#define RED(c) { c += __shfl_xor(c, 8); c += __shfl_xor(c, 16); c += __shfl_xor(c, 32); }
  RED(a0.x) RED(a0.y) RED(a0.z) RED(a0.w)
  RED(a1.x) RED(a1.y) RED(a1.z) RED(a1.w)
#undef RED
  A0 = a0; A1 = a1;
}

__device__ __forceinline__ float4 lk4(float4 x) {
  x.x = x.x >= 0.0f ? x.x : 0.5f * x.x;
  x.y = x.y >= 0.0f ? x.y : 0.5f * x.y;
  x.z = x.z >= 0.0f ? x.z : 0.5f * x.z;
  x.w = x.w >= 0.0f ? x.w : 0.5f * x.w;
  return x;
}

__device__ __forceinline__ uint4 pack8(float4 a, float4 b) {
  uint4 p;
  p.x = f2bf(a.x) | (f2bf(a.y) << 16);
  p.y = f2bf(a.z) | (f2bf(a.w) << 16);
  p.z = f2bf(b.x) | (f2bf(b.y) << 16);
  p.w = f2bf(b.z) | (f2bf(b.w) << 16);
  return p;
}

// Tag-node rows only (rr in [0,TAG_N)): out(bf16) = leaky(tag-spmm row ITEM_N+rr)
__global__ void gather_tagrows_kernel(const int* __restrict__ rp, const int2* __restrict__ rec,
                                      const ushort* __restrict__ srcA, const ushort* __restrict__ srcB,
                                      ushort* __restrict__ out) {
  int rr = (blockIdx.x * blockDim.x + threadIdx.x) >> 6;
  if (rr >= TAG_N) return;
  int lane = threadIdx.x & 63, sub = lane >> 3, fl = lane & 7;
  int r = rr + ITEM_N;
  float4 a0, a1;
  gather_row8<0>(rp[r], rp[r + 1], rec, srcA, srcB, ITEM_N, lane, sub, fl, a0, a1);
  if (sub == 0)
    ((uint4*)(out + (size_t)rr * DD))[fl] = pack8(lk4(a0), lk4(a1));
}

// Mega gather over NN rows; tag gather for item rows fused inline.
// o = leaky(adj) + (r<USER ? leaky(soc) : leaky(tag_row))
// FINAL=false (layer 0): latOut(bf16) = o
// FINAL=true  (layer 1): acc(f32) += f32(lat[row]) + o   (lat = lat1 bf16)
template <int VS, bool FINAL>
__global__ void gather_mega_kernel(
    const int* __restrict__ arp, const int2* __restrict__ arec,
    const int* __restrict__ srp, const int2* __restrict__ srec,
    const int* __restrict__ trp, const int2* __restrict__ trec,
    const ushort* __restrict__ lat,   // NN x 64 bf16: src for adj & soc (& tag items)
    const ushort* __restrict__ tagB,  // tag-node src rows (tEmbf or tg1bf)
    ushort* __restrict__ latOut, float* __restrict__ acc) {
  int r = (blockIdx.x * blockDim.x + threadIdx.x) >> 6;
  if (r >= NN) return;
  int lane = threadIdx.x & 63, sub = lane >> 3, fl = lane & 7;
  float4 t0, t1, b0, b1;
  gather_row8<VS>(arp[r], arp[r + 1], arec, lat, lat, NN, lane, sub, fl, t0, t1);
  if (r < USER_N) {
    gather_row8<VS>(srp[r], srp[r + 1], srec, lat, lat, NN, lane, sub, fl, b0, b1);
  } else {
    int tr = r - USER_N;
    gather_row8<VS>(trp[tr], trp[tr + 1], trec,
                    lat + (size_t)USER_N * DD, tagB, ITEM_N, lane, sub, fl, b0, b1);
  }
  if (sub == 0) {
    t0 = lk4(t0); t1 = lk4(t1); b0 = lk4(b0); b1 = lk4(b1);
    float4 o0 = make_float4(t0.x + b0.x, t0.y + b0.y, t0.z + b0.z, t0.w + b0.w);
    float4 o1 = make_float4(t1.x + b1.x, t1.y + b1.y, t1.z + b1.z, t1.w + b1.w);
    if (FINAL) {
      uint4 l = ((const uint4*)(lat + (size_t)r * DD))[fl];
      float4* ap = (float4*)(acc + (size_t)r * DD);
      float4 v0 = ap[fl * 2], v1 = ap[fl * 2 + 1];
      v0.x += bflo(l.x) + o0.x; v0.y += bfhi(l.x) + o0.y;
      v0.z += bflo(l.y) + o0.z; v0.w += bfhi(l.y) + o0.w;
      v1.x += bflo(l.z) + o1.x; v1.y += bfhi(l.z) + o1.y;
      v1.z += bflo(l.w) + o1.z; v1.w += bfhi(l.w) + o1.w;
      ap[fl * 2] = v0; ap[fl * 2 + 1] = v1;
    } else {
      ((uint4*)(latOut + (size_t)r * DD))[fl] = pack8(o0, o1);
    }
  }
}

// acc(f32) = lat0 = concat(u, i); lat0bf = bf16(lat0); tEmbf = bf16(tEmbeds)
__global__ void init_kernel(const float4* __restrict__ u, const float4* __restrict__ it,
                            const float4* __restrict__ tE,
                            float4* __restrict__ acc, ushort4* __restrict__ lat0bf,
                            ushort4* __restrict__ tEmbf) {
  int idx = blockIdx.x * blockDim.x + threadIdx.x;  // NN*16 + TAG_N*16 float4s
  const int uN = USER_N * 16, nN = NN * 16;
  if (idx < nN) {
    float4 v = (idx < uN) ? u[idx] : it[idx - uN];
    acc[idx] = v;
    ushort4 h;
    h.x = (ushort)f2bf(v.x); h.y = (ushort)f2bf(v.y);
    h.z = (ushort)f2bf(v.z); h.w = (ushort)f2bf(v.w);
    lat0bf[idx] = h;
  } else if (idx < nN + TAG_N * 16) {
    int j = idx - nN;
    float4 v = tE[j];
    ushort4 h;
    h.x = (ushort)f2bf(v.x); h.y = (ushort)f2bf(v.y);
    h.z = (ushort)f2bf(v.z); h.w = (ushort)f2bf(v.w);
    tEmbf[j] = h;
  }
}

extern "C" void kernel_launch(void* const* d_in, const int* in_sizes, int n_in,
                              void* d_out, int out_size, void* d_ws, size_t ws_size,
                              hipStream_t stream) {
  const float* uE    = (const float*)d_in[0];
  const float* iE    = (const float*)d_in[1];
  const float* tEm   = (const float*)d_in[2];
  const int*   adj_r = (const int*)d_in[3];
  const int*   adj_c = (const int*)d_in[4];
  const float* adj_v = (const float*)d_in[5];
  const int*   tag_r = (const int*)d_in[6];
  const int*   tag_c = (const int*)d_in[7];
  const float* tag_v = (const float*)d_in[8];
  const int*   soc_r = (const int*)d_in[9];
  const int*   soc_c = (const int*)d_in[10];
  const float* soc_v = (const float*)d_in[11];
  const int nAdj = in_sizes[5], nTag = in_sizes[8], nSoc = in_sizes[11];

  float* acc = (float*)d_out;

  // Workspace (~86 MB). All bf16 blocks are 16B-aligned (sizes divisible by 16).
  ushort* lat0bf = (ushort*)d_ws;                  // NN*DD bf16
  ushort* lat1bf = lat0bf + (size_t)NN * DD;       // NN*DD
  ushort* tg1bf  = lat1bf + (size_t)NN * DD;       // TAG_N*DD
  ushort* tEmbf  = tg1bf  + (size_t)TAG_N * DD;    // TAG_N*DD
  int2* a_rec = (int2*)(tEmbf + (size_t)TAG_N * DD);  // nAdj {col, bf16v0|bf16v1}
  int2* t_rec = a_rec + nAdj;                      // nTag
  int2* s_rec = t_rec + nTag;                      // nSoc
  int* ip    = (int*)(s_rec + nSoc);
  int* a_rp  = ip;  ip += NN + 1;
  int* a_cur = ip;  ip += NN;
  int* t_rp  = ip;  ip += MM + 1;
  int* t_cur = ip;  ip += MM;
  int* s_rp  = ip;  ip += USER_N + 1;
  int* s_cur = ip;  ip += USER_N;
  int* bsum  = ip;  ip += 256;
  // shared packed-value side array (reused per graph, sequential builds)
  int nPkMax = nAdj > nTag ? nAdj : nTag;
  if (nSoc > nPkMax) nPkMax = nSoc;
  uint32_t* pkbuf = (uint32_t*)ip;  ip += nPkMax;

  // fold_in(key(42), j) for j=0..5 (host-side, deterministic)
  uint32_t kk[6][2];
  for (uint32_t j = 0; j < 6; ++j) tf2x32(0u, 42u, 0u, j, &kk[j][0], &kk[j][1]);

  const int thr = 256;
#define CDIV(a, b) (((a) + (b) - 1) / (b))

  // ---- CSR build (once per call; records carry both layers' values) ----
  struct G { const int* rows; const int* cols; const float* vals; int n; int nE;
             int* rp; int* cur; int2* rec; int k0; int k1; };
  G gs[3] = {
      {adj_r, adj_c, adj_v, NN,     nAdj, a_rp, a_cur, a_rec, 0, 3},
      {tag_r, tag_c, tag_v, MM,     nTag, t_rp, t_cur, t_rec, 1, 4},
      {soc_r, soc_c, soc_v, USER_N, nSoc, s_rp, s_cur, s_rec, 2, 5},
  };
  for (int g = 0; g < 3; ++g) {
    hipMemsetAsync(gs[g].cur, 0, (size_t)gs[g].n * sizeof(int), stream);
    histpack_kernel<<<CDIV(gs[g].nE, thr), thr, 0, stream>>>(
        gs[g].rows, gs[g].vals, gs[g].cur, pkbuf, gs[g].nE,
        kk[gs[g].k0][0], kk[gs[g].k0][1], kk[gs[g].k1][0], kk[gs[g].k1][1]);
    int B = CDIV(gs[g].n, 1024);
    scan1_kernel<<<B, 256, 0, stream>>>(gs[g].cur, gs[g].rp, bsum, gs[g].n);
    scan2_kernel<<<1, 256, 0, stream>>>(bsum, B);
    scan3_kernel<<<CDIV(gs[g].n, thr), thr, 0, stream>>>(gs[g].rp, bsum, gs[g].cur, gs[g].n, gs[g].nE);
    int nSlices = CDIV(gs[g].nE, 4096);
    scatter_part_kernel<<<nSlices * NPART, thr, 0, stream>>>(
        gs[g].rows, gs[g].cols, pkbuf, gs[g].cur, gs[g].rec, gs[g].nE, gs[g].n, nSlices);
  }

  // ---- init: acc = lat0 (f32); lat0bf, tEmbf (bf16 gather sources) ----
  init_kernel<<<CDIV((NN + TAG_N) * 16, thr), thr, 0, stream>>>(
      (const float4*)uE, (const float4*)iE, (const float4*)tEm,
      (float4*)acc, (ushort4*)lat0bf, (ushort4*)tEmbf);

  // ---- layer 0 ----
  // tg1 = leaky(tag-spmm) for tag-node rows (layer-1 tag sources)
  gather_tagrows_kernel<<<CDIV(TAG_N * 64, thr), thr, 0, stream>>>(
      t_rp, t_rec, lat0bf + (size_t)USER_N * DD, tEmbf, tg1bf);

  // lat1 = combine(leaky(adj), leaky(soc) | leaky(tag item rows)); acc untouched
  gather_mega_kernel<0, false><<<CDIV(NN * 64, thr), thr, 0, stream>>>(
      a_rp, a_rec, s_rp, s_rec, t_rp, t_rec, lat0bf, tEmbf, lat1bf, nullptr);

  // ---- layer 1 ----
  // acc += lat1 + combine(leaky(adj), leaky(soc) | leaky(tag item rows))
  gather_mega_kernel<1, true><<<CDIV(NN * 64, thr), thr, 0, stream>>>(
      a_rp, a_rec, s_rp, s_rec, t_rp, t_rec, lat1bf, tg1bf, nullptr, acc);
#undef CDIV
}